// Round 4
// baseline (504.517 us; speedup 1.0000x reference)
//
#include <hip/hip_runtime.h>

// Depthwise "true" 2D convolution: 3072 independent 128x128 fp32 images,
// each with its own 15x15 fp32 kernel, same-padding 7.
// y[i,j] = sum_{a,b} x[i+7-a, j+7-b] * k[a,b]   (zero outside [0,128))
//
// R5 -> R6 change: ILP + addressing cleanup, no algorithmic change.
//  (1) Drop the rowkey XOR (R3->R4 changed the key schedule completely and
//      SQ_LDS_BANK_CONFLICT was bit-identical -> key-irrelevant; residual
//      ~11 cyc/read is the counter tallying the inherent 2-lane/bank
//      aliasing of a wave64 b128, which m136 showed is FREE in time).
//      With key gone, every inner read address = one per-thread base +
//      compile-time immediate (t*608 + {0,16,32,320,336,352} bytes) ->
//      loadx costs ~zero VALU.
//  (2) Software pipeline: ping-pong windows xwA/xwB; issue row t+1's six
//      ds_read_b128 BEFORE row t's 480 FMAs. Because kern s_loads share
//      lgkmcnt with ds_reads (out-of-order -> compiler must drain fully at
//      first kv use), each step runs the 3 fmarows on already-resident
//      kernel rows FIRST and the fmarow needing this step's fresh kernel
//      row LAST, putting ~720 FMA cycles between prefetch issue and drain.
//  (3) Division-free staging loop (incremental row/m), LDS 49920->47424 B.

namespace {

constexpr int P      = 128;           // patch size
constexpr int K      = 15;            // kernel size
constexpr int HALF   = 64;            // output rows per block
constexpr int LROWS  = HALF + K - 1;  // 78 staged rows
constexpr int LM     = 36;            // logical float4 slots per row (144 floats)
constexpr int LWP    = 152;           // physical row width in floats (38 slots;
                                      // dein image = [0,17] u [20,37])
constexpr int NT     = 256;

__device__ __forceinline__ int dein(int m) {
    // de-interleave even/odd logical float4 slots
    return (m >> 1) + (m & 1) * 20;
}

__global__ __launch_bounds__(NT, 3)
void dwconv_kernel(const float* __restrict__ patches,
                   const float* __restrict__ kernels,
                   float* __restrict__ out)
{
    __shared__ float xs[LROWS * LWP];  // 47424 B input strip

    const int tid   = threadIdx.x;
    const int n     = blockIdx.x >> 1;        // image index 0..3071
    const int halfb = blockIdx.x & 1;
    const int ibase = halfb * HALF;           // first output row of this block

    const float* img  = patches + (size_t)n * (P * P);
    const float* kern = kernels + (size_t)n * (K * K);

    // ---- stage input strip rows [ibase-7, ibase+70] with zero halo ----
    // incremental (row, m) walk: idx += 256 == row += 7, m += 4 (mod 36)
    {
        int row = tid / LM;
        int m   = tid - row * LM;
        while (row < LROWS) {
            const int r  = ibase - 7 + row;    // global input row
            const int g0 = m * 4 - 8;          // global col of first float
            float4 v = make_float4(0.f, 0.f, 0.f, 0.f);
            if ((unsigned)r < (unsigned)P) {
                if (g0 >= 0 && g0 + 3 < P) {
                    v = *reinterpret_cast<const float4*>(img + r * P + g0);
                } else {
                    float t0 = 0.f, t1 = 0.f, t2 = 0.f, t3 = 0.f;
                    const float* rp = img + r * P;
                    if ((unsigned)(g0 + 0) < (unsigned)P) t0 = rp[g0 + 0];
                    if ((unsigned)(g0 + 1) < (unsigned)P) t1 = rp[g0 + 1];
                    if ((unsigned)(g0 + 2) < (unsigned)P) t2 = rp[g0 + 2];
                    if ((unsigned)(g0 + 3) < (unsigned)P) t3 = rp[g0 + 3];
                    v = make_float4(t0, t1, t2, t3);
                }
            }
            *reinterpret_cast<float4*>(xs + row * LWP + 4 * dein(m)) = v;
            row += 7; m += 4;
            if (m >= LM) { m -= LM; ++row; }
        }
    }
    __syncthreads();

    // ---- per-thread 4x8 output tile, strip-row-major, pipelined ----
    const int ty = tid >> 4;       // 0..15
    const int tx = tid & 15;       // 0..15
    const int i0 = ty * 4;         // local output row base (0..60)
    const int j0 = tx * 8;         // output col base (0..120)

    // slot m = 2*tx + q -> dein = tx + (q>>1) + 20*(q&1)
    // float offsets from (xs + i0*LWP + 4*tx): t*LWP + {0,80,4,84,8,88}
    const float* xbase = xs + i0 * LWP + 4 * tx;

    float acc[4][8];
    #pragma unroll
    for (int rr = 0; rr < 4; ++rr)
        #pragma unroll
        for (int s = 0; s < 8; ++s)
            acc[rr][s] = 0.0f;

    float xwA[24], xwB[24];        // ping-pong row windows (cols j0-8..j0+15)
    float kr[4][K];                // rolling kernel rows (wave-uniform -> SGPR)

#define LOADX(W, t) do {                                                     \
        const float* xr_ = xbase + (t) * LWP;                                \
        const float4 v0_ = *reinterpret_cast<const float4*>(xr_ + 0);        \
        const float4 v1_ = *reinterpret_cast<const float4*>(xr_ + 80);       \
        const float4 v2_ = *reinterpret_cast<const float4*>(xr_ + 4);        \
        const float4 v3_ = *reinterpret_cast<const float4*>(xr_ + 84);       \
        const float4 v4_ = *reinterpret_cast<const float4*>(xr_ + 8);        \
        const float4 v5_ = *reinterpret_cast<const float4*>(xr_ + 88);       \
        W[0]=v0_.x;  W[1]=v0_.y;  W[2]=v0_.z;  W[3]=v0_.w;                   \
        W[4]=v1_.x;  W[5]=v1_.y;  W[6]=v1_.z;  W[7]=v1_.w;                   \
        W[8]=v2_.x;  W[9]=v2_.y;  W[10]=v2_.z; W[11]=v2_.w;                  \
        W[12]=v3_.x; W[13]=v3_.y; W[14]=v3_.z; W[15]=v3_.w;                  \
        W[16]=v4_.x; W[17]=v4_.y; W[18]=v4_.z; W[19]=v4_.w;                  \
        W[20]=v5_.x; W[21]=v5_.y; W[22]=v5_.z; W[23]=v5_.w;                  \
    } while (0)

#define FMAROW(W, rr, slot) do {                                             \
        _Pragma("unroll")                                                    \
        for (int b_ = 0; b_ < K; ++b_)                                       \
            _Pragma("unroll")                                                \
            for (int s_ = 0; s_ < 8; ++s_)                                   \
                acc[rr][s_] = fmaf(W[s_ + 15 - b_], kr[slot][b_],            \
                                   acc[rr][s_]);                             \
    } while (0)

    // slot argument is always a literal -> static kr indexing
    auto loadk = [&](int slot, int a) {
        #pragma unroll
        for (int b = 0; b < K; ++b) kr[slot][b] = kern[a * K + b];
    };

    // head: t = 0,1,2  (kernel rows 14,13,12 -> slots 2,1,0)
    loadk(2, 14); loadk(1, 13); loadk(0, 12);
    LOADX(xwA, 0);
    // t=0 (cur A)
    LOADX(xwB, 1);
    FMAROW(xwA, 0, 2);
    // t=1 (cur B)
    LOADX(xwA, 2);
    FMAROW(xwB, 0, 1); FMAROW(xwB, 1, 2);
    // t=2 (cur A)
    LOADX(xwB, 3);
    FMAROW(xwA, 0, 0); FMAROW(xwA, 1, 1); FMAROW(xwA, 2, 2);

    // steady state: t = 3..14; 4 steps per iter keeps window parity static.
    // At step t the NEW kernel row feeds rr=0 -> run it last (drain point).
    #pragma unroll 1
    for (int tb = 3; tb <= 11; tb += 4) {
        // t = tb+0, cur B
        loadk(3, 14 - tb); LOADX(xwA, tb + 1);
        FMAROW(xwB, 1, 0); FMAROW(xwB, 2, 1); FMAROW(xwB, 3, 2);
        FMAROW(xwB, 0, 3);
        // t = tb+1, cur A
        loadk(2, 13 - tb); LOADX(xwB, tb + 2);
        FMAROW(xwA, 1, 3); FMAROW(xwA, 2, 0); FMAROW(xwA, 3, 1);
        FMAROW(xwA, 0, 2);
        // t = tb+2, cur B
        loadk(1, 12 - tb); LOADX(xwA, tb + 3);
        FMAROW(xwB, 1, 2); FMAROW(xwB, 2, 3); FMAROW(xwB, 3, 0);
        FMAROW(xwB, 0, 1);
        // t = tb+3, cur A
        loadk(0, 11 - tb); LOADX(xwB, tb + 4);
        FMAROW(xwA, 1, 1); FMAROW(xwA, 2, 2); FMAROW(xwA, 3, 3);
        FMAROW(xwA, 0, 0);
    }

    // tail: t = 15,16,17 (all kernel rows resident)
    // t=15, cur B
    LOADX(xwA, 16);
    FMAROW(xwB, 1, 0); FMAROW(xwB, 2, 1); FMAROW(xwB, 3, 2);
    // t=16, cur A
    LOADX(xwB, 17);
    FMAROW(xwA, 2, 0); FMAROW(xwA, 3, 1);
    // t=17, cur B
    FMAROW(xwB, 3, 0);

#undef LOADX
#undef FMAROW

    // ---- write 4x8 tile ----
    float* orow = out + (size_t)n * (P * P) + (size_t)(ibase + i0) * P + j0;
    #pragma unroll
    for (int rr = 0; rr < 4; ++rr) {
        *reinterpret_cast<float4*>(orow + rr * P + 0) =
            make_float4(acc[rr][0], acc[rr][1], acc[rr][2], acc[rr][3]);
        *reinterpret_cast<float4*>(orow + rr * P + 4) =
            make_float4(acc[rr][4], acc[rr][5], acc[rr][6], acc[rr][7]);
    }
}

} // namespace

extern "C" void kernel_launch(void* const* d_in, const int* in_sizes, int n_in,
                              void* d_out, int out_size, void* d_ws, size_t ws_size,
                              hipStream_t stream) {
    const float* patches = (const float*)d_in[0];
    const float* kernels = (const float*)d_in[1];
    float* out = (float*)d_out;

    const int n_images = in_sizes[0] / (P * P);   // 3072
    const int grid = n_images * 2;                // 2 blocks per image

    dwconv_kernel<<<grid, NT, 0, stream>>>(patches, kernels, out);
}

// Round 5
// 498.009 us; speedup vs baseline: 1.0131x; 1.0131x over previous
//
#include <hip/hip_runtime.h>

// Depthwise "true" 2D convolution: 3072 independent 128x128 fp32 images,
// each with its own 15x15 fp32 kernel, same-padding 7.
// y[i,j] = sum_{a,b} x[i+7-a, j+7-b] * k[a,b]   (zero outside [0,128))
//
// R6 -> R7 change: occupancy. R5/R6 plateaued at ~290us with VALUBusy ~71%,
// FMA-issue only 49%, occupancy 32.5% (47.6KB LDS -> 3 blocks/CU -> 3
// waves/SIMD). Pipelining and addressing tweaks were both neutral -> the
// idle is cross-wave (staging latency into the barrier, block ramp/drain),
// fixable only with more resident waves. Quarter-image blocks: HALF=32,
// LROWS=46, LDS=29.4KB -> 5 blocks/CU = 5 waves/SIMD (+67% TLP).
// Per-thread tile 2x8 (ty 0..15 x 2 rows); rolling 2-row kernel window.
// Layout reverts to the best-measured R5 variant: LWP=160 + rowkey
// (R6 showed LWP=152/no-key puts ty-groups 4 rows apart on the same bank).

namespace {

constexpr int P      = 128;           // patch size
constexpr int K      = 15;            // kernel size
constexpr int HALF   = 32;            // output rows per block
constexpr int LROWS  = HALF + K - 1;  // 46 staged rows
constexpr int LM     = 36;            // logical float4 slots per row (144 floats)
constexpr int LWP    = 160;           // physical row width in floats (40 slots)
constexpr int NT     = 256;

__device__ __forceinline__ int dein(int m) {
    // de-interleave even/odd logical float4 slots
    return (m >> 1) + (m & 1) * 20;
}

__device__ __forceinline__ int rowkey(int row) {
    // rows 2/4/6 apart in one instruction get distinct, even-XOR keys
    return (row >> 1) & 6;
}

__global__ __launch_bounds__(NT, 5)
void dwconv_kernel(const float* __restrict__ patches,
                   const float* __restrict__ kernels,
                   float* __restrict__ out)
{
    __shared__ float xs[LROWS * LWP];  // 29440 B input strip

    const int tid   = threadIdx.x;
    const int n     = blockIdx.x >> 2;        // image index 0..3071
    const int qb    = blockIdx.x & 3;
    const int ibase = qb * HALF;              // first output row of this block

    const float* img  = patches + (size_t)n * (P * P);
    const float* kern = kernels + (size_t)n * (K * K);

    // ---- stage input strip rows [ibase-7, ibase+38] with zero halo ----
    // incremental (row, m) walk: idx += 256 == row += 7, m += 4 (mod 36)
    {
        int row = tid / LM;
        int m   = tid - row * LM;
        while (row < LROWS) {
            const int r  = ibase - 7 + row;    // global input row
            const int g0 = m * 4 - 8;          // global col of first float
            float4 v = make_float4(0.f, 0.f, 0.f, 0.f);
            if ((unsigned)r < (unsigned)P) {
                if (g0 >= 0 && g0 + 3 < P) {
                    v = *reinterpret_cast<const float4*>(img + r * P + g0);
                } else {
                    float t0 = 0.f, t1 = 0.f, t2 = 0.f, t3 = 0.f;
                    const float* rp = img + r * P;
                    if ((unsigned)(g0 + 0) < (unsigned)P) t0 = rp[g0 + 0];
                    if ((unsigned)(g0 + 1) < (unsigned)P) t1 = rp[g0 + 1];
                    if ((unsigned)(g0 + 2) < (unsigned)P) t2 = rp[g0 + 2];
                    if ((unsigned)(g0 + 3) < (unsigned)P) t3 = rp[g0 + 3];
                    v = make_float4(t0, t1, t2, t3);
                }
            }
            *reinterpret_cast<float4*>(xs + row * LWP + 4 * (dein(m) ^ rowkey(row))) = v;
            row += 7; m += 4;
            if (m >= LM) { m -= LM; ++row; }
        }
    }
    __syncthreads();

    // ---- per-thread 2x8 output tile, strip-row-major, pipelined ----
    const int ty = tid >> 4;       // 0..15
    const int tx = tid & 15;       // 0..15
    const int i0 = ty * 2;         // local output row base (0..30)
    const int j0 = tx * 8;         // output col base (0..120)

    // logical slots per row: m = 2*tx + q -> dein = tx + (q>>1) + 20*(q&1)
    const int dbase[6] = { tx + 0, tx + 20, tx + 1, tx + 21, tx + 2, tx + 22 };

    float acc[2][8];
    #pragma unroll
    for (int rr = 0; rr < 2; ++rr)
        #pragma unroll
        for (int s = 0; s < 8; ++s)
            acc[rr][s] = 0.0f;

    float xwA[24], xwB[24];        // ping-pong row windows (cols j0-8..j0+15)
    float kr0[K], kr1[K];          // rolling kernel rows (wave-uniform -> SGPR)

#define LOADX(W, t) do {                                                     \
        const int    lrow_ = i0 + (t);                                       \
        const float* xr_   = xs + lrow_ * LWP;                               \
        const int    key_  = (lrow_ >> 1) & 6;                               \
        _Pragma("unroll")                                                    \
        for (int q_ = 0; q_ < 6; ++q_) {                                     \
            const float4 v_ =                                                \
                *reinterpret_cast<const float4*>(xr_ + 4 * (dbase[q_] ^ key_)); \
            W[q_ * 4 + 0] = v_.x; W[q_ * 4 + 1] = v_.y;                      \
            W[q_ * 4 + 2] = v_.z; W[q_ * 4 + 3] = v_.w;                      \
        }                                                                    \
    } while (0)

#define FMAROW(W, rr, KR) do {                                               \
        _Pragma("unroll")                                                    \
        for (int b_ = 0; b_ < K; ++b_)                                       \
            _Pragma("unroll")                                                \
            for (int s_ = 0; s_ < 8; ++s_)                                   \
                acc[rr][s_] = fmaf(W[s_ + 15 - b_], KR[b_], acc[rr][s_]);    \
    } while (0)

    auto loadk = [&](float (&kr)[K], int a) {
        #pragma unroll
        for (int b = 0; b < K; ++b) kr[b] = kern[a * K + b];
    };

    // strip row tt feeds output rr with kernel row a = rr + 14 - tt:
    //   rr=0: a = 14-tt (tt 0..14), rr=1: a = 15-tt (tt 1..15)
    // -> one new kernel row per step, 2-slot ping-pong; fresh row used LAST.
    LOADX(xwA, 0);
    loadk(kr0, 14);
    // tt = 0 (cur A)
    LOADX(xwB, 1);
    FMAROW(xwA, 0, kr0);

    #pragma unroll 1
    for (int ttb = 1; ttb <= 13; ttb += 2) {
        // tt = ttb (cur B): rr1 uses prev row (kr0), rr0 uses fresh (kr1)
        loadk(kr1, 14 - ttb); LOADX(xwA, ttb + 1);
        FMAROW(xwB, 1, kr0);
        FMAROW(xwB, 0, kr1);
        // tt = ttb+1 (cur A)
        loadk(kr0, 13 - ttb); LOADX(xwB, ttb + 2);
        FMAROW(xwA, 1, kr1);
        FMAROW(xwA, 0, kr0);
    }
    // tt = 15 (cur B): rr1 with a = 0 (in kr0 from ttb=13 second substep)
    FMAROW(xwB, 1, kr0);

#undef LOADX
#undef FMAROW

    // ---- write 2x8 tile ----
    float* orow = out + (size_t)n * (P * P) + (size_t)(ibase + i0) * P + j0;
    #pragma unroll
    for (int rr = 0; rr < 2; ++rr) {
        *reinterpret_cast<float4*>(orow + rr * P + 0) =
            make_float4(acc[rr][0], acc[rr][1], acc[rr][2], acc[rr][3]);
        *reinterpret_cast<float4*>(orow + rr * P + 4) =
            make_float4(acc[rr][4], acc[rr][5], acc[rr][6], acc[rr][7]);
    }
}

} // namespace

extern "C" void kernel_launch(void* const* d_in, const int* in_sizes, int n_in,
                              void* d_out, int out_size, void* d_ws, size_t ws_size,
                              hipStream_t stream) {
    const float* patches = (const float*)d_in[0];
    const float* kernels = (const float*)d_in[1];
    float* out = (float*)d_out;

    const int n_images = in_sizes[0] / (P * P);   // 3072
    const int grid = n_images * 4;                // 4 quarter blocks per image

    dwconv_kernel<<<grid, NT, 0, stream>>>(patches, kernels, out);
}

// Round 7
// 489.060 us; speedup vs baseline: 1.0316x; 1.0183x over previous
//
#include <hip/hip_runtime.h>

// Depthwise "true" 2D convolution: 3072 independent 128x128 fp32 images,
// each with its own 15x15 fp32 kernel, same-padding 7.
// y[i,j] = sum_{a,b} x[i+7-a, j+7-b] * k[a,b]   (zero outside [0,128))
//
// R8 (resubmit; previous run died on a container infra failure, no data).
// R7 -> R8 change: zero-VALU inner-loop addressing. R7 hit VALUBusy 86.6%
// with dur unchanged -> issue-bound; ~105us of the 249us VALU issue is
// non-FMA, dominated by per-read LDS address math (XOR key forces a
// computed address per ds_read: ~340 VALU/thread). Fix: drop the rowkey
// (R6 measured LWP=152/no-key time-neutral; its rows-4-apart 2-way
// aliasing is in the free band per m136), keep the even/odd de-interleave
// (which kills the real 4-way stride-32B conflict), and emit ALL 96 inner
// ds_read_b128 as immediate-offset reads from ONE per-thread base VGPR:
// byte offset = t*608 + {0,320,16,336,32,352}, max 9472 < 64K.
// Inner loop = FMAs + bare ds_reads (ds issue uses the LDS pipe, not VALU).

namespace {

constexpr int P      = 128;           // patch size
constexpr int K      = 15;            // kernel size
constexpr int HALF   = 32;            // output rows per block
constexpr int LROWS  = HALF + K - 1;  // 46 staged rows
constexpr int LM     = 36;            // logical float4 slots per row (144 floats)
constexpr int LWP    = 152;           // physical row width in floats
                                      // (dein image [0,17] u [20,37] = 38 slots)
constexpr int NT     = 256;

__device__ __forceinline__ int dein(int m) {
    // de-interleave even/odd logical float4 slots
    return (m >> 1) + (m & 1) * 20;
}

__global__ __launch_bounds__(NT, 5)
void dwconv_kernel(const float* __restrict__ patches,
                   const float* __restrict__ kernels,
                   float* __restrict__ out)
{
    __shared__ float xs[LROWS * LWP];  // 27968 B input strip -> 5 blocks/CU

    const int tid   = threadIdx.x;
    const int n     = blockIdx.x >> 2;        // image index 0..3071
    const int qb    = blockIdx.x & 3;
    const int ibase = qb * HALF;              // first output row of this block

    const float* img  = patches + (size_t)n * (P * P);
    const float* kern = kernels + (size_t)n * (K * K);

    // ---- stage input strip rows [ibase-7, ibase+38] with zero halo ----
    // incremental (row, m) walk: idx += 256 == row += 7, m += 4 (mod 36)
    {
        int row = tid / LM;
        int m   = tid - row * LM;
        while (row < LROWS) {
            const int r  = ibase - 7 + row;    // global input row
            const int g0 = m * 4 - 8;          // global col of first float
            float4 v = make_float4(0.f, 0.f, 0.f, 0.f);
            if ((unsigned)r < (unsigned)P) {
                if (g0 >= 0 && g0 + 3 < P) {
                    v = *reinterpret_cast<const float4*>(img + r * P + g0);
                } else {
                    float t0 = 0.f, t1 = 0.f, t2 = 0.f, t3 = 0.f;
                    const float* rp = img + r * P;
                    if ((unsigned)(g0 + 0) < (unsigned)P) t0 = rp[g0 + 0];
                    if ((unsigned)(g0 + 1) < (unsigned)P) t1 = rp[g0 + 1];
                    if ((unsigned)(g0 + 2) < (unsigned)P) t2 = rp[g0 + 2];
                    if ((unsigned)(g0 + 3) < (unsigned)P) t3 = rp[g0 + 3];
                    v = make_float4(t0, t1, t2, t3);
                }
            }
            *reinterpret_cast<float4*>(xs + row * LWP + 4 * dein(m)) = v;
            row += 7; m += 4;
            if (m >= LM) { m -= LM; ++row; }
        }
    }
    __syncthreads();

    // ---- per-thread 2x8 output tile, strip-row-major, pipelined ----
    const int ty = tid >> 4;       // 0..15
    const int tx = tid & 15;       // 0..15
    const int i0 = ty * 2;         // local output row base (0..30)
    const int j0 = tx * 8;         // output col base (0..120)

    // single base register; every inner read = base + compile-time offset
    const float* lp = xs + i0 * LWP + 4 * tx;

    float acc[2][8];
    #pragma unroll
    for (int rr = 0; rr < 2; ++rr)
        #pragma unroll
        for (int s = 0; s < 8; ++s)
            acc[rr][s] = 0.0f;

    float xwA[24], xwB[24];        // ping-pong row windows (cols j0-8..j0+15)
    float kr0[K], kr1[K];          // rolling kernel rows (wave-uniform -> SGPR)

    // slot m = 2*tx + q -> dein = tx + (q>>1) + 20*(q&1)
    // float offsets from lp: t*152 + {0,80,4,84,8,88}   (T is a literal)
#define LOADX(W, T) do {                                                     \
        const float4 v0_ = *reinterpret_cast<const float4*>(lp + (T)*152 + 0);  \
        const float4 v1_ = *reinterpret_cast<const float4*>(lp + (T)*152 + 80); \
        const float4 v2_ = *reinterpret_cast<const float4*>(lp + (T)*152 + 4);  \
        const float4 v3_ = *reinterpret_cast<const float4*>(lp + (T)*152 + 84); \
        const float4 v4_ = *reinterpret_cast<const float4*>(lp + (T)*152 + 8);  \
        const float4 v5_ = *reinterpret_cast<const float4*>(lp + (T)*152 + 88); \
        W[0]=v0_.x;  W[1]=v0_.y;  W[2]=v0_.z;  W[3]=v0_.w;                   \
        W[4]=v1_.x;  W[5]=v1_.y;  W[6]=v1_.z;  W[7]=v1_.w;                   \
        W[8]=v2_.x;  W[9]=v2_.y;  W[10]=v2_.z; W[11]=v2_.w;                  \
        W[12]=v3_.x; W[13]=v3_.y; W[14]=v3_.z; W[15]=v3_.w;                  \
        W[16]=v4_.x; W[17]=v4_.y; W[18]=v4_.z; W[19]=v4_.w;                  \
        W[20]=v5_.x; W[21]=v5_.y; W[22]=v5_.z; W[23]=v5_.w;                  \
    } while (0)

#define FMAROW(W, rr, KR) do {                                               \
        _Pragma("unroll")                                                    \
        for (int b_ = 0; b_ < K; ++b_)                                       \
            _Pragma("unroll")                                                \
            for (int s_ = 0; s_ < 8; ++s_)                                   \
                acc[rr][s_] = fmaf(W[s_ + 15 - b_], KR[b_], acc[rr][s_]);    \
    } while (0)

    auto loadk = [&](float (&kr)[K], int a) {
        #pragma unroll
        for (int b = 0; b < K; ++b) kr[b] = kern[a * K + b];
    };

    // strip row tt feeds output rr with kernel row a = rr + 14 - tt:
    //   rr=0: a = 14-tt (tt 0..14), rr=1: a = 15-tt (tt 1..15)
    // -> one new kernel row per step, 2-slot ping-pong; fresh row used LAST.
    LOADX(xwA, 0);
    loadk(kr0, 14);
    // tt = 0 (cur A)
    LOADX(xwB, 1);
    FMAROW(xwA, 0, kr0);

    #pragma unroll 1
    for (int ttb = 1; ttb <= 13; ttb += 2) {
        // tt = ttb (cur B): rr1 uses prev row (kr0), rr0 uses fresh (kr1)
        loadk(kr1, 14 - ttb); LOADX(xwA, ttb + 1);
        FMAROW(xwB, 1, kr0);
        FMAROW(xwB, 0, kr1);
        // tt = ttb+1 (cur A)
        loadk(kr0, 13 - ttb); LOADX(xwB, ttb + 2);
        FMAROW(xwA, 1, kr1);
        FMAROW(xwA, 0, kr0);
    }
    // tt = 15 (cur B): rr1 with a = 0 (in kr0 from ttb=13 second substep)
    FMAROW(xwB, 1, kr0);

#undef LOADX
#undef FMAROW

    // ---- write 2x8 tile ----
    float* orow = out + (size_t)n * (P * P) + (size_t)(ibase + i0) * P + j0;
    #pragma unroll
    for (int rr = 0; rr < 2; ++rr) {
        *reinterpret_cast<float4*>(orow + rr * P + 0) =
            make_float4(acc[rr][0], acc[rr][1], acc[rr][2], acc[rr][3]);
        *reinterpret_cast<float4*>(orow + rr * P + 4) =
            make_float4(acc[rr][4], acc[rr][5], acc[rr][6], acc[rr][7]);
    }
}

} // namespace

extern "C" void kernel_launch(void* const* d_in, const int* in_sizes, int n_in,
                              void* d_out, int out_size, void* d_ws, size_t ws_size,
                              hipStream_t stream) {
    const float* patches = (const float*)d_in[0];
    const float* kernels = (const float*)d_in[1];
    float* out = (float*)d_out;

    const int n_images = in_sizes[0] / (P * P);   // 3072
    const int grid = n_images * 4;                // 4 quarter blocks per image

    dwconv_kernel<<<grid, NT, 0, stream>>>(patches, kernels, out);
}